// Round 1
// 221.796 us; speedup vs baseline: 1.0000x; 1.0000x over previous
//
#include <hip/hip_runtime.h>
#include <math.h>

// Problem constants (fixed by the reference)
#define T_    1024      // B*S tokens
#define H_    512       // hidden
#define I_    1024      // intermediate
#define E_    64        // routed experts
#define K_    4         // top-k
#define NPAIR (T_*K_)   // 4096 routed (token,slot) pairs
#define NENT  (NPAIR + T_)  // + shared-expert entries at [NPAIR + t]

#define BM 64
#define BN 64
#define BKS 64          // k-step (bf16 elements)
#define LDP 72          // padded LDS row (elements): 144 B stride -> 2-way max on frag reads
#define MAXWORK 160     // >= worst-case row-block count (128 routed + 16 shared)

typedef float  f32x4  __attribute__((ext_vector_type(4)));
typedef short  bf16x8 __attribute__((ext_vector_type(8)));

__device__ __forceinline__ ushort f2bf(float f) {
    uint u = __float_as_uint(f);
    u += 0x7fffu + ((u >> 16) & 1u);   // round-to-nearest-even
    return (ushort)(u >> 16);
}

// ---------------------------------------------------------------------------
// Router: one 64-thread block per token.
// ---------------------------------------------------------------------------
__global__ __launch_bounds__(64) void moe_router(
    const float* __restrict__ x, const float* __restrict__ rw,
    const float* __restrict__ rb, const float* __restrict__ eb,
    int* __restrict__ idx_out, float* __restrict__ gate_out)
{
    const int t = blockIdx.x;
    const int lane = threadIdx.x;  // 0..63
    __shared__ float xs[H_];
    __shared__ float lg[E_];
    __shared__ float bs[E_];
    for (int i = lane; i < H_; i += 64) xs[i] = x[(size_t)t*H_ + i];
    bs[lane] = eb[lane];
    __syncthreads();
    float acc = 0.f;
    const float* wrow = rw + (size_t)lane*H_;
    for (int k = 0; k < H_; k += 4) {
        float4 w4 = *reinterpret_cast<const float4*>(wrow + k);
        acc = fmaf(xs[k+0], w4.x, acc);
        acc = fmaf(xs[k+1], w4.y, acc);
        acc = fmaf(xs[k+2], w4.z, acc);
        acc = fmaf(xs[k+3], w4.w, acc);
    }
    lg[lane] = acc + rb[lane];
    __syncthreads();
    if (lane == 0) {
        unsigned long long used = 0ull;
        int sel[K_]; float orig[K_];
        for (int k = 0; k < K_; ++k) {
            float best = -INFINITY; int bi = 0;
            for (int e = 0; e < E_; ++e) {
                if (used & (1ull << e)) continue;
                float v = lg[e] + bs[e];
                if (v > best) { best = v; bi = e; }   // strict > : lowest idx on tie
            }
            used |= (1ull << bi);
            sel[k] = bi; orig[k] = lg[bi];
        }
        float s[K_]; float sum = 0.f;
        for (int k = 0; k < K_; ++k) { s[k] = 1.f/(1.f + __expf(-orig[k])); sum += s[k]; }
        sum = fmaxf(sum, 1e-12f);
        for (int k = 0; k < K_; ++k) {
            idx_out[t*K_ + k] = sel[k];
            gate_out[t*K_ + k] = s[k] / sum;
        }
    }
}

// ---------------------------------------------------------------------------
// Build per-expert token lists + flattened row-block work list (single block).
// ---------------------------------------------------------------------------
__global__ __launch_bounds__(256) void moe_build(
    const int* __restrict__ idx, const float* __restrict__ gates,
    int* __restrict__ cnts, int* __restrict__ offs,
    int* __restrict__ entry_token, float* __restrict__ entry_gate,
    int* __restrict__ pair_pos,
    int* __restrict__ blk_e, int* __restrict__ blk_ro, int* __restrict__ nwork)
{
    __shared__ int c[E_];
    __shared__ int run[E_];
    const int tid = threadIdx.x;
    if (tid < E_) c[tid] = 0;
    __syncthreads();
    for (int p = tid; p < NPAIR; p += 256) atomicAdd(&c[idx[p]], 1);
    __syncthreads();
    if (tid == 0) {
        int o = 0;
        for (int e = 0; e < E_; ++e) { run[e] = o; offs[e] = o; cnts[e] = c[e]; o += c[e]; }
        offs[E_] = NPAIR;   // shared-expert entries
        cnts[E_] = T_;
        int nb = 0;
        for (int e = 0; e <= E_; ++e) {
            int n = (e < E_) ? c[e] : T_;
            for (int ro = 0; ro < n; ro += BM) { blk_e[nb] = e; blk_ro[nb] = ro; ++nb; }
        }
        nwork[0] = nb;
    }
    __syncthreads();
    for (int p = tid; p < NPAIR; p += 256) {
        int e = idx[p];
        int pos = atomicAdd(&run[e], 1);
        entry_token[pos] = p / K_;
        entry_gate[pos]  = gates[p];
        pair_pos[p]      = pos;
    }
    for (int t = tid; t < T_; t += 256) {
        entry_token[NPAIR + t] = t;
        entry_gate[NPAIR + t]  = 1.0f;
    }
}

// ---------------------------------------------------------------------------
// Stage 1 (MFMA bf16): h1 = silu(X w1^T + b1) * (X w3^T + b3)  -> bf16
// Software-pipelined: all 12 staging loads for step k+1 issued back-to-back
// while MFMA(k) runs. Row pointers hoisted out of the K-loop.
// ---------------------------------------------------------------------------
__global__ __launch_bounds__(256) void moe_stage1(
    const float* __restrict__ x,
    const float* __restrict__ w1, const float* __restrict__ b1,
    const float* __restrict__ w3, const float* __restrict__ b3,
    const float* __restrict__ sw1, const float* __restrict__ sb1,
    const float* __restrict__ sw3, const float* __restrict__ sb3,
    const int* __restrict__ cnts, const int* __restrict__ offs,
    const int* __restrict__ entry_token,
    const int* __restrict__ blk_e, const int* __restrict__ blk_ro,
    const int* __restrict__ nwork,
    ushort* __restrict__ h1buf)
{
    const int w = blockIdx.x;
    if (w >= nwork[0]) return;
    const int e  = blk_e[w];
    const int ro = blk_ro[w];
    const int itile = blockIdx.y;   // 0..I_/BN-1
    const int n = cnts[e];
    const int off = offs[e];
    const int rows = min(BM, n - ro);
    const float* W1 = (e < E_) ? (w1 + (size_t)e*I_*H_) : sw1;
    const float* W3 = (e < E_) ? (w3 + (size_t)e*I_*H_) : sw3;
    const float* B1 = (e < E_) ? (b1 + (size_t)e*I_) : sb1;
    const float* B3 = (e < E_) ? (b3 + (size_t)e*I_) : sb3;

    __shared__ ushort Xs [BM][LDP];
    __shared__ ushort W1s[BN][LDP];
    __shared__ ushort W3s[BN][LDP];

    const int tid  = threadIdx.x;
    const int lane = tid & 63;
    const int wid  = tid >> 6;          // 0..3
    const int wm   = wid >> 1;          // wave row   (0..1) -> 32 rows
    const int wn   = wid & 1;           // wave col   (0..1) -> 32 cols
    const int l15  = lane & 15;
    const int lg   = lane >> 4;         // 0..3

    const int sr = tid >> 4;            // staging row base 0..15
    const int sc = tid & 15;            // 16B column chunk 0..15

    // K-invariant row pointers (gather indices hoisted out of the K-loop).
    // Rows beyond 'rows' read a neighboring valid entry; the resulting
    // garbage only lands in output rows >= rows, which the epilogue masks.
    const float* xp[4];
    const float* wp[4];
    #pragma unroll
    for (int i = 0; i < 4; ++i) {
        int r = sr + i*16;
        xp[i] = x + (size_t)entry_token[off + ro + r]*H_ + sc*4;
        wp[i] = W1 + (size_t)(itile*BN + r)*H_ + sc*4;
    }
    const ptrdiff_t d31 = (const float*)W3 - (const float*)W1;

    f32x4 acc1[2][2] = {};
    f32x4 acc3[2][2] = {};

    // prologue: issue all 12 loads for k-step 0
    float4 xv[4], av[4], cv[4];
    #pragma unroll
    for (int i = 0; i < 4; ++i) {
        xv[i] = *reinterpret_cast<const float4*>(xp[i]);
        av[i] = *reinterpret_cast<const float4*>(wp[i]);
        cv[i] = *reinterpret_cast<const float4*>(wp[i] + d31);
    }

    for (int kc = 0; kc < H_; kc += BKS) {
        const int kc2 = (kc + BKS) & (H_ - 1);   // wraps to 0 on last iter (values unused)
        __syncthreads();                          // prev MFMA done reading LDS
        // convert + write step k (data issued a full K-step ago -> arrived)
        #pragma unroll
        for (int i = 0; i < 4; ++i) {
            *reinterpret_cast<ushort4*>(&Xs [sr + i*16][sc*4]) =
                make_ushort4(f2bf(xv[i].x), f2bf(xv[i].y), f2bf(xv[i].z), f2bf(xv[i].w));
            *reinterpret_cast<ushort4*>(&W1s[sr + i*16][sc*4]) =
                make_ushort4(f2bf(av[i].x), f2bf(av[i].y), f2bf(av[i].z), f2bf(av[i].w));
            *reinterpret_cast<ushort4*>(&W3s[sr + i*16][sc*4]) =
                make_ushort4(f2bf(cv[i].x), f2bf(cv[i].y), f2bf(cv[i].z), f2bf(cv[i].w));
        }
        // issue step k+1 loads back-to-back (12-deep MLP, overlap with MFMA)
        #pragma unroll
        for (int i = 0; i < 4; ++i) {
            xv[i] = *reinterpret_cast<const float4*>(xp[i] + kc2);
            av[i] = *reinterpret_cast<const float4*>(wp[i] + kc2);
            cv[i] = *reinterpret_cast<const float4*>(wp[i] + kc2 + d31);
        }
        __syncthreads();
        #pragma unroll
        for (int s = 0; s < 2; ++s) {       // two K=32 slices per 64-k tile
            bf16x8 a[2], bb1[2], bb3[2];
            #pragma unroll
            for (int f = 0; f < 2; ++f) {
                a[f]   = *reinterpret_cast<const bf16x8*>(&Xs [wm*32 + f*16 + l15][s*32 + lg*8]);
                bb1[f] = *reinterpret_cast<const bf16x8*>(&W1s[wn*32 + f*16 + l15][s*32 + lg*8]);
                bb3[f] = *reinterpret_cast<const bf16x8*>(&W3s[wn*32 + f*16 + l15][s*32 + lg*8]);
            }
            #pragma unroll
            for (int fm = 0; fm < 2; ++fm) {
                #pragma unroll
                for (int fn = 0; fn < 2; ++fn) {
                    acc1[fm][fn] = __builtin_amdgcn_mfma_f32_16x16x32_bf16(a[fm], bb1[fn], acc1[fm][fn], 0, 0, 0);
                    acc3[fm][fn] = __builtin_amdgcn_mfma_f32_16x16x32_bf16(a[fm], bb3[fn], acc3[fm][fn], 0, 0, 0);
                }
            }
        }
    }
    // epilogue: silu(z1)*z3 -> bf16
    #pragma unroll
    for (int fm = 0; fm < 2; ++fm) {
        #pragma unroll
        for (int fn = 0; fn < 2; ++fn) {
            const int col = itile*BN + wn*32 + fn*16 + l15;
            const float bv1 = B1[col];
            const float bv3 = B3[col];
            #pragma unroll
            for (int j = 0; j < 4; ++j) {
                const int rl = wm*32 + fm*16 + lg*4 + j;   // C/D: row=(lane>>4)*4+reg, col=lane&15
                if (rl < rows) {
                    float z1 = acc1[fm][fn][j] + bv1;
                    float z3 = acc3[fm][fn][j] + bv3;
                    float h = z1 / (1.f + __expf(-z1)) * z3;
                    h1buf[(size_t)(off+ro+rl)*I_ + col] = f2bf(h);
                }
            }
        }
    }
}

// ---------------------------------------------------------------------------
// Stage 2 (MFMA bf16): y = gate * (h1 @ w2^T + b2) -> ybuf fp32
// Same software pipeline: 6 staging loads/thread issued a full K-step early.
// ---------------------------------------------------------------------------
__global__ __launch_bounds__(256) void moe_stage2(
    const ushort* __restrict__ h1buf,
    const float* __restrict__ w2, const float* __restrict__ b2,
    const float* __restrict__ sw2, const float* __restrict__ sb2,
    const int* __restrict__ cnts, const int* __restrict__ offs,
    const float* __restrict__ entry_gate,
    const int* __restrict__ blk_e, const int* __restrict__ blk_ro,
    const int* __restrict__ nwork,
    float* __restrict__ ybuf)
{
    const int w = blockIdx.x;
    if (w >= nwork[0]) return;
    const int e  = blk_e[w];
    const int ro = blk_ro[w];
    const int htile = blockIdx.y;   // 0..H_/BN-1
    const int n = cnts[e];
    const int off = offs[e];
    const int rows = min(BM, n - ro);
    const float* W2 = (e < E_) ? (w2 + (size_t)e*H_*I_) : sw2;
    const float* B2 = (e < E_) ? (b2 + (size_t)e*H_) : sb2;

    __shared__ ushort Hs[BM][LDP];
    __shared__ ushort Ws[BN][LDP];

    const int tid  = threadIdx.x;
    const int lane = tid & 63;
    const int wid  = tid >> 6;
    const int wm   = wid >> 1;
    const int wn   = wid & 1;
    const int l15  = lane & 15;
    const int lg   = lane >> 4;

    const int sr = tid >> 4;            // 0..15 (weight staging)
    const int sc = tid & 15;
    const int hr = tid >> 3;            // 0..31 (h1 staging)
    const int hc = tid & 7;

    // K-invariant row pointers. h1buf rows beyond 'rows' belong to a
    // neighboring entry (always initialized by stage1); garbage is masked.
    const ushort* hp[2];
    const float*  wp[4];
    #pragma unroll
    for (int i = 0; i < 2; ++i)
        hp[i] = h1buf + (size_t)(off + ro + hr + i*32)*I_ + hc*8;
    #pragma unroll
    for (int i = 0; i < 4; ++i)
        wp[i] = W2 + (size_t)(htile*BN + sr + i*16)*I_ + sc*4;

    f32x4 acc[2][2] = {};

    // prologue: issue loads for k-step 0
    uint4  hv[2];
    float4 wv[4];
    #pragma unroll
    for (int i = 0; i < 2; ++i) hv[i] = *reinterpret_cast<const uint4*>(hp[i]);
    #pragma unroll
    for (int i = 0; i < 4; ++i) wv[i] = *reinterpret_cast<const float4*>(wp[i]);

    for (int kc = 0; kc < I_; kc += BKS) {
        const int kc2 = (kc + BKS) & (I_ - 1);
        __syncthreads();
        // write step k
        #pragma unroll
        for (int i = 0; i < 2; ++i)
            *reinterpret_cast<uint4*>(&Hs[hr + i*32][hc*8]) = hv[i];
        #pragma unroll
        for (int i = 0; i < 4; ++i)
            *reinterpret_cast<ushort4*>(&Ws[sr + i*16][sc*4]) =
                make_ushort4(f2bf(wv[i].x), f2bf(wv[i].y), f2bf(wv[i].z), f2bf(wv[i].w));
        // issue step k+1
        #pragma unroll
        for (int i = 0; i < 2; ++i)
            hv[i] = *reinterpret_cast<const uint4*>(hp[i] + kc2);
        #pragma unroll
        for (int i = 0; i < 4; ++i)
            wv[i] = *reinterpret_cast<const float4*>(wp[i] + kc2);
        __syncthreads();
        #pragma unroll
        for (int s = 0; s < 2; ++s) {
            bf16x8 a[2], b[2];
            #pragma unroll
            for (int f = 0; f < 2; ++f) {
                a[f] = *reinterpret_cast<const bf16x8*>(&Hs[wm*32 + f*16 + l15][s*32 + lg*8]);
                b[f] = *reinterpret_cast<const bf16x8*>(&Ws[wn*32 + f*16 + l15][s*32 + lg*8]);
            }
            #pragma unroll
            for (int fm = 0; fm < 2; ++fm) {
                #pragma unroll
                for (int fn = 0; fn < 2; ++fn) {
                    acc[fm][fn] = __builtin_amdgcn_mfma_f32_16x16x32_bf16(a[fm], b[fn], acc[fm][fn], 0, 0, 0);
                }
            }
        }
    }
    #pragma unroll
    for (int fm = 0; fm < 2; ++fm) {
        #pragma unroll
        for (int fn = 0; fn < 2; ++fn) {
            const int col = htile*BN + wn*32 + fn*16 + l15;
            const float bv = B2[col];
            #pragma unroll
            for (int j = 0; j < 4; ++j) {
                const int rl = wm*32 + fm*16 + lg*4 + j;
                if (rl < rows) {
                    const float g = entry_gate[off + ro + rl];
                    ybuf[(size_t)(off+ro+rl)*H_ + col] = (acc[fm][fn][j] + bv) * g;
                }
            }
        }
    }
}

// ---------------------------------------------------------------------------
// Combine: out[t] = y_shared[t] + sum_k y_routed[pair_pos[t,k]]
// ---------------------------------------------------------------------------
__global__ __launch_bounds__(128) void moe_combine(
    const float* __restrict__ ybuf, const int* __restrict__ pair_pos,
    float* __restrict__ out)
{
    const int t = blockIdx.x;
    const int lane = threadIdx.x;     // 128 threads * 4 floats = 512
    const int h = lane * 4;
    const int p0 = pair_pos[t*K_+0], p1 = pair_pos[t*K_+1];
    const int p2 = pair_pos[t*K_+2], p3 = pair_pos[t*K_+3];
    float4 a  = *reinterpret_cast<const float4*>(ybuf + (size_t)(NPAIR+t)*H_ + h);
    float4 v0 = *reinterpret_cast<const float4*>(ybuf + (size_t)p0*H_ + h);
    float4 v1 = *reinterpret_cast<const float4*>(ybuf + (size_t)p1*H_ + h);
    float4 v2 = *reinterpret_cast<const float4*>(ybuf + (size_t)p2*H_ + h);
    float4 v3 = *reinterpret_cast<const float4*>(ybuf + (size_t)p3*H_ + h);
    float4 r;
    r.x = a.x + v0.x + v1.x + v2.x + v3.x;
    r.y = a.y + v0.y + v1.y + v2.y + v3.y;
    r.z = a.z + v0.z + v1.z + v2.z + v3.z;
    r.w = a.w + v0.w + v1.w + v2.w + v3.w;
    *reinterpret_cast<float4*>(out + (size_t)t*H_ + h) = r;
}

extern "C" void kernel_launch(void* const* d_in, const int* in_sizes, int n_in,
                              void* d_out, int out_size, void* d_ws, size_t ws_size,
                              hipStream_t stream)
{
    const float* x   = (const float*)d_in[0];
    const float* rw  = (const float*)d_in[1];
    const float* rb  = (const float*)d_in[2];
    const float* eb  = (const float*)d_in[3];
    const float* sw1 = (const float*)d_in[4];
    const float* sb1 = (const float*)d_in[5];
    const float* sw2 = (const float*)d_in[6];
    const float* sb2 = (const float*)d_in[7];
    const float* sw3 = (const float*)d_in[8];
    const float* sb3 = (const float*)d_in[9];
    const float* w1  = (const float*)d_in[10];
    const float* b1  = (const float*)d_in[11];
    const float* w2  = (const float*)d_in[12];
    const float* b2  = (const float*)d_in[13];
    const float* w3  = (const float*)d_in[14];
    const float* b3  = (const float*)d_in[15];
    float* out = (float*)d_out;

    char* p = (char*)d_ws;
    auto take = [&](size_t bytes) { char* q = p; p += (bytes + 255) & ~(size_t)255; return q; };
    int*    idxb  = (int*)   take((size_t)NPAIR*4);
    float*  gateb = (float*) take((size_t)NPAIR*4);
    int*    cnts  = (int*)   take((E_+1)*4);
    int*    offs  = (int*)   take((E_+1)*4);
    int*    etok  = (int*)   take((size_t)NENT*4);
    float*  egate = (float*) take((size_t)NENT*4);
    int*    ppos  = (int*)   take((size_t)NPAIR*4);
    int*    blk_e = (int*)   take((size_t)MAXWORK*4);
    int*    blk_ro= (int*)   take((size_t)MAXWORK*4);
    int*    nwork = (int*)   take(4);
    ushort* h1buf = (ushort*)take((size_t)NENT*I_*2);
    float*  ybuf  = (float*) take((size_t)NENT*H_*4);

    moe_router <<<T_, 64, 0, stream>>>(x, rw, rb, eb, idxb, gateb);
    moe_build  <<<1, 256, 0, stream>>>(idxb, gateb, cnts, offs, etok, egate, ppos,
                                       blk_e, blk_ro, nwork);
    moe_stage1 <<<dim3(MAXWORK, I_/BN), 256, 0, stream>>>(x, w1, b1, w3, b3,
                                                          sw1, sb1, sw3, sb3,
                                                          cnts, offs, etok,
                                                          blk_e, blk_ro, nwork, h1buf);
    moe_stage2 <<<dim3(MAXWORK, H_/BN), 256, 0, stream>>>(h1buf, w2, b2, sw2, sb2,
                                                          cnts, offs, egate,
                                                          blk_e, blk_ro, nwork, ybuf);
    moe_combine<<<T_, 128, 0, stream>>>(ybuf, ppos, out);
}